// Round 6
// baseline (192.285 us; speedup 1.0000x reference)
//
#include <hip/hip_runtime.h>
#include <cstdint>
#include <cstddef>

#define C_DIM 256
#define N_PIX 10000
#define B_SZ 16

// ---------------- k_wpe: wpe[o][p] = sum_c W[o][c] * pe[c][p]  (o: cls0,cls1,bb0..3) ----
__global__ __launch_bounds__(256) void k_wpe(const float* __restrict__ pe,
    const float* __restrict__ Wc, const float* __restrict__ Wb, float* __restrict__ wpe) {
  int p = blockIdx.x * 256 + threadIdx.x;   // grid (10, 6)
  int o = blockIdx.y;
  if (p >= 2500) return;
  const float* W = (o < 2) ? (Wc + o * C_DIM) : (Wb + (o - 2) * C_DIM);
  float acc = 0.f;
#pragma unroll 8
  for (int c = 0; c < C_DIM; ++c) acc = fmaf(W[c], pe[c * 2500 + p], acc);
  wpe[o * 2500 + p] = acc;
}

// ---------------- fused cls/bbox/conf over x (the 164MB kernel), 1 px/thread ------------
__global__ __launch_bounds__(256, 4) void k_heads(
    const float* __restrict__ x, const float* __restrict__ wpe,
    const float* __restrict__ Wc, const float* __restrict__ bc,
    const float* __restrict__ Wb, const float* __restrict__ bb,
    float* __restrict__ cls, float* __restrict__ bbox, float* __restrict__ conf) {
  __shared__ float w[6][C_DIM];
  int tid = threadIdx.x;
  w[0][tid] = Wc[tid];
  w[1][tid] = Wc[C_DIM + tid];
  w[2][tid] = Wb[tid];
  w[3][tid] = Wb[C_DIM + tid];
  w[4][tid] = Wb[2 * C_DIM + tid];
  w[5][tid] = Wb[3 * C_DIM + tid];
  __syncthreads();
  int b = blockIdx.y;
  int n = blockIdx.x * 256 + tid;            // grid (40, 16)
  if (n >= N_PIX) return;
  const float* xb = x + (size_t)b * C_DIM * N_PIX + n;
  float a0 = 0.f, a1 = 0.f, a2 = 0.f, a3 = 0.f, a4 = 0.f, a5 = 0.f;
#pragma unroll 8
  for (int c = 0; c < C_DIM; c += 4) {
    float x0 = xb[(size_t)(c + 0) * N_PIX];
    float x1 = xb[(size_t)(c + 1) * N_PIX];
    float x2 = xb[(size_t)(c + 2) * N_PIX];
    float x3 = xb[(size_t)(c + 3) * N_PIX];
    float4 w0 = *(const float4*)(&w[0][c]);
    float4 w1 = *(const float4*)(&w[1][c]);
    float4 w2 = *(const float4*)(&w[2][c]);
    float4 w3 = *(const float4*)(&w[3][c]);
    float4 w4 = *(const float4*)(&w[4][c]);
    float4 w5 = *(const float4*)(&w[5][c]);
    a0 = fmaf(w0.x, x0, a0); a0 = fmaf(w0.y, x1, a0); a0 = fmaf(w0.z, x2, a0); a0 = fmaf(w0.w, x3, a0);
    a1 = fmaf(w1.x, x0, a1); a1 = fmaf(w1.y, x1, a1); a1 = fmaf(w1.z, x2, a1); a1 = fmaf(w1.w, x3, a1);
    a2 = fmaf(w2.x, x0, a2); a2 = fmaf(w2.y, x1, a2); a2 = fmaf(w2.z, x2, a2); a2 = fmaf(w2.w, x3, a2);
    a3 = fmaf(w3.x, x0, a3); a3 = fmaf(w3.y, x1, a3); a3 = fmaf(w3.z, x2, a3); a3 = fmaf(w3.w, x3, a3);
    a4 = fmaf(w4.x, x0, a4); a4 = fmaf(w4.y, x1, a4); a4 = fmaf(w4.z, x2, a4); a4 = fmaf(w4.w, x3, a4);
    a5 = fmaf(w5.x, x0, a5); a5 = fmaf(w5.y, x1, a5); a5 = fmaf(w5.z, x2, a5); a5 = fmaf(w5.w, x3, a5);
  }
  int y = n / 100, xq = n % 100;
  float sy = fminf(fmaxf((y + 0.5f) * 0.5f - 0.5f, 0.0f), 49.0f);
  float sx = fminf(fmaxf((xq + 0.5f) * 0.5f - 0.5f, 0.0f), 49.0f);
  int y0 = (int)floorf(sy); int y1 = min(y0 + 1, 49); float ty = sy - (float)y0;
  int x0i = (int)floorf(sx); int x1i = min(x0i + 1, 49); float tx = sx - (float)x0i;
  float pd[6];
#pragma unroll
  for (int o = 0; o < 6; ++o) {
    const float* m = wpe + o * 2500;
    float v00 = m[y0 * 50 + x0i], v01 = m[y0 * 50 + x1i];
    float v10 = m[y1 * 50 + x0i], v11 = m[y1 * 50 + x1i];
    float r0 = v00 * (1.0f - ty) + v10 * ty;
    float r1 = v01 * (1.0f - ty) + v11 * ty;
    pd[o] = r0 * (1.0f - tx) + r1 * tx;
  }
  float c0 = a0 + pd[0] + bc[0];
  float c1 = a1 + pd[1] + bc[1];
  float b0 = a2 + pd[2] + bb[0];
  float b1 = a3 + pd[3] + bb[1];
  float b2 = a4 + pd[4] + bb[2];
  float b3 = a5 + pd[5] + bb[3];
  size_t nb = (size_t)b * N_PIX + n;
  float2 cv; cv.x = c0; cv.y = c1;
  *(float2*)(cls + nb * 2) = cv;
  float4 bv; bv.x = b0; bv.y = b1; bv.z = b2; bv.w = b3;
  *(float4*)(bbox + nb * 4) = bv;
  float m0 = fmaxf(c0, c1);
  float e0 = expf(c0 - m0), e1 = expf(c1 - m0);
  conf[nb] = e1 / (e0 + e1);
}

// ---------------- top-k phase 1: per-(batch,chunk of 1250) local top>=100 ----------------
__global__ __launch_bounds__(256) void k_topk1(const float* __restrict__ conf,
    unsigned long long* __restrict__ candbuf, unsigned int* __restrict__ cntbuf) {
  __shared__ unsigned int ordl[1250];
  __shared__ unsigned int whist[4][256];
  __shared__ unsigned int hist[256];
  __shared__ unsigned int s_cnt, s_prefix, s_nc;
  int tid = threadIdx.x;
  int wv = tid >> 6;
  int chunk = blockIdx.x, b = blockIdx.y;
  int base = chunk * 1250;
  const float* cb = conf + (size_t)b * N_PIX + base;
  for (int i = tid; i < 1250; i += 256) {
    unsigned int u = __float_as_uint(cb[i]);
    ordl[i] = (u & 0x80000000u) ? ~u : (u | 0x80000000u);
  }
  unsigned int prefix = 0, cnt_gt = 0;
  for (int pass = 0; pass < 4; ++pass) {
    int sh = 24 - 8 * pass;
    for (int i = tid; i < 4 * 256; i += 256) ((unsigned int*)whist)[i] = 0;
    __syncthreads();
    unsigned int himask = (pass == 0) ? 0u : (0xFFFFFFFFu << (sh + 8));
    for (int i = tid; i < 1250; i += 256) {
      unsigned int o = ordl[i];
      if ((o & himask) == prefix) atomicAdd(&whist[wv][(o >> sh) & 255u], 1u);
    }
    __syncthreads();
    if (tid < 256) {
      unsigned int s = whist[0][tid] + whist[1][tid] + whist[2][tid] + whist[3][tid];
      hist[tid] = s;
    }
    __syncthreads();
    if (tid == 0) {
      unsigned int c = cnt_gt; int v = 255;
      while (v > 0 && c + hist[v] < 100u) { c += hist[v]; --v; }
      s_cnt = c; s_prefix = prefix | ((unsigned int)v << sh);
    }
    __syncthreads();
    cnt_gt = s_cnt; prefix = s_prefix;
    __syncthreads();
  }
  if (tid == 0) s_nc = 0;
  __syncthreads();
  unsigned int T = prefix;
  unsigned long long* cb_out = candbuf + (size_t)(b * 8 + chunk) * 512;
  for (int i = tid; i < 1250; i += 256) {
    unsigned int o = ordl[i];
    if (o >= T) {
      unsigned int k = atomicAdd(&s_nc, 1u);
      if (k < 512u)
        cb_out[k] = ((unsigned long long)o << 32) |
                    (unsigned long long)(0xFFFFFFFFu - (unsigned int)(base + i));
    }
  }
  __syncthreads();
  if (tid == 0) cntbuf[b * 8 + chunk] = s_nc > 512u ? 512u : s_nc;
}

// ---------------- top-k phase 2: merge 8 chunks' candidates -> top-100 ------------------
__global__ __launch_bounds__(256) void k_topk2(
    const unsigned long long* __restrict__ candbuf, const unsigned int* __restrict__ cntbuf,
    int* __restrict__ idx_out) {
  __shared__ unsigned long long keys[4096];
  __shared__ unsigned int whist[4][256];
  __shared__ unsigned int hist[256];
  __shared__ unsigned long long cand2[256];
  __shared__ unsigned int s_cnt, s_prefix, s_nc;
  int tid = threadIdx.x;
  int wv = tid >> 6;
  int b = blockIdx.x;
  for (int s = tid; s < 4096; s += 256) {
    int ci = s >> 9, i = s & 511;
    unsigned int c = cntbuf[b * 8 + ci];
    keys[s] = ((unsigned int)i < c) ? candbuf[(size_t)(b * 8 + ci) * 512 + i] : 0ull;
  }
  __syncthreads();
  unsigned int prefix = 0, cnt_gt = 0;
  for (int pass = 0; pass < 4; ++pass) {
    int sh = 24 - 8 * pass;
    for (int i = tid; i < 4 * 256; i += 256) ((unsigned int*)whist)[i] = 0;
    __syncthreads();
    unsigned int himask = (pass == 0) ? 0u : (0xFFFFFFFFu << (sh + 8));
    for (int s = tid; s < 4096; s += 256) {
      unsigned int o = (unsigned int)(keys[s] >> 32);
      if ((o & himask) == prefix) atomicAdd(&whist[wv][(o >> sh) & 255u], 1u);
    }
    __syncthreads();
    if (tid < 256) {
      unsigned int s = whist[0][tid] + whist[1][tid] + whist[2][tid] + whist[3][tid];
      hist[tid] = s;
    }
    __syncthreads();
    if (tid == 0) {
      unsigned int c = cnt_gt; int v = 255;
      while (v > 0 && c + hist[v] < 100u) { c += hist[v]; --v; }
      s_cnt = c; s_prefix = prefix | ((unsigned int)v << sh);
    }
    __syncthreads();
    cnt_gt = s_cnt; prefix = s_prefix;
    __syncthreads();
  }
  if (tid == 0) s_nc = 0;
  __syncthreads();
  unsigned int T = prefix;
  for (int s = tid; s < 4096; s += 256) {
    unsigned int o = (unsigned int)(keys[s] >> 32);
    if (o >= T) {
      unsigned int k = atomicAdd(&s_nc, 1u);
      if (k < 256u) cand2[k] = keys[s];
    }
  }
  __syncthreads();
  unsigned int nc = s_nc > 256u ? 256u : s_nc;
  if (tid >= nc) cand2[tid] = 0ull;
  __syncthreads();
  for (unsigned int k = 2; k <= 256; k <<= 1) {
    for (unsigned int j = k >> 1; j > 0; j >>= 1) {
      unsigned int i = (unsigned int)tid, ixj = i ^ j;
      if (ixj > i) {
        unsigned long long a = cand2[i], c2 = cand2[ixj];
        bool up = ((i & k) == 0);
        if ((a > c2) == up) { cand2[i] = c2; cand2[ixj] = a; }
      }
      __syncthreads();
    }
  }
  if (tid < 100) {
    unsigned long long key = cand2[255 - tid];
    idx_out[b * 100 + tid] = (int)(0xFFFFFFFFu - (unsigned int)(key & 0xFFFFFFFFull));
  }
}

// ---------------- fused gather (+inline pos) + 3-layer MLP, R=5 rows/block --------------
#define R_ROWS 5

__device__ __forceinline__ void mlp_layer5(const float (*in)[C_DIM], float (*outb)[C_DIM],
    const float* __restrict__ W, const float* __restrict__ bias, bool relu, int tid) {
  float acc[R_ROWS];
  float bv = bias[tid];
#pragma unroll
  for (int r = 0; r < R_ROWS; ++r) acc[r] = bv;
  const float* wrow = W + (size_t)tid * C_DIM;
#pragma unroll 4
  for (int c = 0; c < C_DIM; c += 4) {
    float4 w4 = *(const float4*)(wrow + c);
#pragma unroll
    for (int r = 0; r < R_ROWS; ++r) {
      float4 iv = *(const float4*)(&in[r][c]);
      float s = fmaf(w4.x, iv.x, acc[r]);
      s = fmaf(w4.y, iv.y, s);
      s = fmaf(w4.z, iv.z, s);
      acc[r] = fmaf(w4.w, iv.w, s);
    }
  }
#pragma unroll
  for (int r = 0; r < R_ROWS; ++r) outb[r][tid] = relu ? fmaxf(acc[r], 0.0f) : acc[r];
  __syncthreads();
}

// grid.x = 320 (det: 16 b x 20 chunks) + 80 (rec: 16 b x 5 chunks) = 400
__global__ __launch_bounds__(256) void k_mlp2(
    const float* __restrict__ x, const float* __restrict__ pe, const int* __restrict__ idx,
    const float* __restrict__ dW1, const float* __restrict__ db1,
    const float* __restrict__ dW2, const float* __restrict__ db2,
    const float* __restrict__ dW3, const float* __restrict__ db3,
    const float* __restrict__ rW1, const float* __restrict__ rb1,
    const float* __restrict__ rW2, const float* __restrict__ rb2,
    const float* __restrict__ rW3, const float* __restrict__ rb3,
    const float* __restrict__ det_q, const float* __restrict__ rec_q,
    float* __restrict__ det, float* __restrict__ rec) {
  __shared__ float bufA[R_ROWS][C_DIM];
  __shared__ float bufB[R_ROWS][C_DIM];
  int tid = threadIdx.x;
  int cid = blockIdx.x;
  int b, r0, rpb;
  const float *W1, *B1, *W2, *B2, *W3, *B3, *q;
  float* outp;
  if (cid < 320) {
    b = cid / 20; r0 = (cid % 20) * R_ROWS; rpb = 100;
    W1 = dW1; B1 = db1; W2 = dW2; B2 = db2; W3 = dW3; B3 = db3;
    q = det_q; outp = det;
  } else {
    int c2 = cid - 320;
    b = c2 / 5; r0 = (c2 % 5) * R_ROWS; rpb = 25;
    W1 = rW1; B1 = rb1; W2 = rW2; B2 = rb2; W3 = rW3; B3 = rb3;
    q = rec_q; outp = rec;
  }
  // gather x + recomputed pos (bilinear of pe at selected pixel), c = tid
#pragma unroll
  for (int r = 0; r < R_ROWS; ++r) {
    int n = idx[b * 100 + r0 + r];
    int y = n / 100, xq = n % 100;
    float sy = fminf(fmaxf((y + 0.5f) * 0.5f - 0.5f, 0.0f), 49.0f);
    float sx = fminf(fmaxf((xq + 0.5f) * 0.5f - 0.5f, 0.0f), 49.0f);
    int y0 = (int)floorf(sy); int y1 = min(y0 + 1, 49); float ty = sy - (float)y0;
    int x0i = (int)floorf(sx); int x1i = min(x0i + 1, 49); float tx = sx - (float)x0i;
    const float* p = pe + tid * 2500;
    float v00 = p[y0 * 50 + x0i], v01 = p[y0 * 50 + x1i];
    float v10 = p[y1 * 50 + x0i], v11 = p[y1 * 50 + x1i];
    float rr0 = v00 * (1.0f - ty) + v10 * ty;
    float rr1 = v01 * (1.0f - ty) + v11 * ty;
    float pv = rr0 * (1.0f - tx) + rr1 * tx;
    bufA[r][tid] = x[((size_t)b * C_DIM + tid) * N_PIX + n] + pv;
  }
  __syncthreads();
  mlp_layer5(bufA, bufB, W1, B1, true, tid);
  mlp_layer5(bufB, bufA, W2, B2, true, tid);
  mlp_layer5(bufA, bufB, W3, B3, false, tid);
#pragma unroll
  for (int r = 0; r < R_ROWS; ++r) {
    int rr = r0 + r;
    outp[((size_t)b * rpb + rr) * C_DIM + tid] = bufB[r][tid] + q[rr * C_DIM + tid];
  }
}

extern "C" void kernel_launch(void* const* d_in, const int* in_sizes, int n_in,
                              void* d_out, int out_size, void* d_ws, size_t ws_size,
                              hipStream_t stream) {
  const float* x     = (const float*)d_in[0];
  const float* Wc    = (const float*)d_in[1];
  const float* bc    = (const float*)d_in[2];
  const float* Wb    = (const float*)d_in[3];
  const float* bb    = (const float*)d_in[4];
  const float* dW1   = (const float*)d_in[5];
  const float* db1   = (const float*)d_in[6];
  const float* dW2   = (const float*)d_in[7];
  const float* db2   = (const float*)d_in[8];
  const float* dW3   = (const float*)d_in[9];
  const float* db3   = (const float*)d_in[10];
  const float* rW1   = (const float*)d_in[11];
  const float* rb1   = (const float*)d_in[12];
  const float* rW2   = (const float*)d_in[13];
  const float* rb2   = (const float*)d_in[14];
  const float* rW3   = (const float*)d_in[15];
  const float* rb3   = (const float*)d_in[16];
  const float* det_q = (const float*)d_in[17];
  const float* rec_q = (const float*)d_in[18];
  const float* pos_e = (const float*)d_in[19];

  float* out  = (float*)d_out;
  float* det  = out;                // [16,100,256]  409600
  float* rec  = out + 409600;       // [16, 25,256]  102400
  float* cls  = out + 512000;       // [16,10000,2]  320000
  float* bbox = out + 832000;       // [16,10000,4]  640000

  // ws layout (bytes):
  //   candbuf u64[16*8*512] @ 0        (524288 B)
  //   conf    f32[160000]   @ 524288   (640000 B)
  //   idx     i32[2048]     @ 1164288
  //   wpe     f32[15000]    @ 1172480
  //   cnt     u32[128]      @ 1232480
  char* wsb = (char*)d_ws;
  unsigned long long* candbuf = (unsigned long long*)wsb;
  float* conf = (float*)(wsb + 524288);
  int*   idx  = (int*)(wsb + 1164288);
  float* wpe  = (float*)(wsb + 1172480);
  unsigned int* cnt = (unsigned int*)(wsb + 1232480);

  k_wpe<<<dim3(10, 6), 256, 0, stream>>>(pos_e, Wc, Wb, wpe);
  k_heads<<<dim3(40, B_SZ), 256, 0, stream>>>(x, wpe, Wc, bc, Wb, bb, cls, bbox, conf);
  k_topk1<<<dim3(8, B_SZ), 256, 0, stream>>>(conf, candbuf, cnt);
  k_topk2<<<B_SZ, 256, 0, stream>>>(candbuf, cnt, idx);
  k_mlp2<<<400, 256, 0, stream>>>(x, pos_e, idx,
                                  dW1, db1, dW2, db2, dW3, db3,
                                  rW1, rb1, rW2, rb2, rW3, rb3,
                                  det_q, rec_q, det, rec);
}

// Round 7
// 140.355 us; speedup vs baseline: 1.3700x; 1.3700x over previous
//
#include <hip/hip_runtime.h>
#include <cstdint>
#include <cstddef>

#define C_DIM 256
#define N_PIX 10000
#define B_SZ 16

// ---------------- k_prep (R5-verified): wpe (blocks 0..59) + tiled transpose (60..155) --
__global__ __launch_bounds__(256) void k_prep(
    const float* __restrict__ pe,
    const float* __restrict__ Wc, const float* __restrict__ Wb,
    const float* __restrict__ dW1, const float* __restrict__ dW2, const float* __restrict__ dW3,
    const float* __restrict__ rW1, const float* __restrict__ rW2, const float* __restrict__ rW3,
    float* __restrict__ wpe, float* __restrict__ wT) {
  __shared__ float tile[64][65];
  int tid = threadIdx.x;
  int bid = blockIdx.x;
  if (bid < 60) {
    int o = bid / 10;
    int p = (bid % 10) * 256 + tid;
    if (p >= 2500) return;
    const float* W = (o < 2) ? (Wc + o * C_DIM) : (Wb + (o - 2) * C_DIM);
    float acc = 0.f;
#pragma unroll 8
    for (int c = 0; c < C_DIM; ++c) acc = fmaf(W[c], pe[c * 2500 + p], acc);
    wpe[o * 2500 + p] = acc;
    return;
  }
  int t = bid - 60;            // 96 blocks: 6 matrices x 16 (64x64) tiles
  int m = t >> 4;
  int tl = t & 15;
  int ty = tl >> 2, tx = tl & 3;
  const float* W;
  switch (m) {
    case 0: W = dW1; break;
    case 1: W = dW2; break;
    case 2: W = dW3; break;
    case 3: W = rW1; break;
    case 4: W = rW2; break;
    default: W = rW3; break;
  }
  int lane = tid & 63, rg = tid >> 6;
  for (int rr = rg; rr < 64; rr += 4)
    tile[rr][lane] = W[(size_t)(ty * 64 + rr) * 256 + tx * 64 + lane];
  __syncthreads();
  for (int rr = rg; rr < 64; rr += 4)
    wT[(size_t)m * 65536 + (size_t)(tx * 64 + rr) * 256 + ty * 64 + lane] = tile[lane][rr];
}

// ---------------- fused cls/bbox/conf over x (R4-exact) ---------------------------------
__global__ __launch_bounds__(256, 4) void k_heads(
    const float* __restrict__ x, const float* __restrict__ wpe,
    const float* __restrict__ Wc, const float* __restrict__ bc,
    const float* __restrict__ Wb, const float* __restrict__ bb,
    float* __restrict__ cls, float* __restrict__ bbox, float* __restrict__ conf) {
  __shared__ float w[6][C_DIM];
  int tid = threadIdx.x;
  w[0][tid] = Wc[tid];
  w[1][tid] = Wc[C_DIM + tid];
  w[2][tid] = Wb[tid];
  w[3][tid] = Wb[C_DIM + tid];
  w[4][tid] = Wb[2 * C_DIM + tid];
  w[5][tid] = Wb[3 * C_DIM + tid];
  __syncthreads();
  int b = blockIdx.y;
  int n = blockIdx.x * 256 + tid;            // grid (40, 16)
  if (n >= N_PIX) return;
  const float* xb = x + (size_t)b * C_DIM * N_PIX + n;
  float a0 = 0.f, a1 = 0.f, a2 = 0.f, a3 = 0.f, a4 = 0.f, a5 = 0.f;
#pragma unroll 4
  for (int c = 0; c < C_DIM; c += 4) {
    float x0 = xb[(size_t)(c + 0) * N_PIX];
    float x1 = xb[(size_t)(c + 1) * N_PIX];
    float x2 = xb[(size_t)(c + 2) * N_PIX];
    float x3 = xb[(size_t)(c + 3) * N_PIX];
    float4 w0 = *(const float4*)(&w[0][c]);
    float4 w1 = *(const float4*)(&w[1][c]);
    float4 w2 = *(const float4*)(&w[2][c]);
    float4 w3 = *(const float4*)(&w[3][c]);
    float4 w4 = *(const float4*)(&w[4][c]);
    float4 w5 = *(const float4*)(&w[5][c]);
    a0 = fmaf(w0.x, x0, a0); a0 = fmaf(w0.y, x1, a0); a0 = fmaf(w0.z, x2, a0); a0 = fmaf(w0.w, x3, a0);
    a1 = fmaf(w1.x, x0, a1); a1 = fmaf(w1.y, x1, a1); a1 = fmaf(w1.z, x2, a1); a1 = fmaf(w1.w, x3, a1);
    a2 = fmaf(w2.x, x0, a2); a2 = fmaf(w2.y, x1, a2); a2 = fmaf(w2.z, x2, a2); a2 = fmaf(w2.w, x3, a2);
    a3 = fmaf(w3.x, x0, a3); a3 = fmaf(w3.y, x1, a3); a3 = fmaf(w3.z, x2, a3); a3 = fmaf(w3.w, x3, a3);
    a4 = fmaf(w4.x, x0, a4); a4 = fmaf(w4.y, x1, a4); a4 = fmaf(w4.z, x2, a4); a4 = fmaf(w4.w, x3, a4);
    a5 = fmaf(w5.x, x0, a5); a5 = fmaf(w5.y, x1, a5); a5 = fmaf(w5.z, x2, a5); a5 = fmaf(w5.w, x3, a5);
  }
  int y = n / 100, xq = n % 100;
  float sy = fminf(fmaxf((y + 0.5f) * 0.5f - 0.5f, 0.0f), 49.0f);
  float sx = fminf(fmaxf((xq + 0.5f) * 0.5f - 0.5f, 0.0f), 49.0f);
  int y0 = (int)floorf(sy); int y1 = min(y0 + 1, 49); float ty = sy - (float)y0;
  int x0i = (int)floorf(sx); int x1i = min(x0i + 1, 49); float tx = sx - (float)x0i;
  float pd[6];
#pragma unroll
  for (int o = 0; o < 6; ++o) {
    const float* m = wpe + o * 2500;
    float v00 = m[y0 * 50 + x0i], v01 = m[y0 * 50 + x1i];
    float v10 = m[y1 * 50 + x0i], v11 = m[y1 * 50 + x1i];
    float r0 = v00 * (1.0f - ty) + v10 * ty;
    float r1 = v01 * (1.0f - ty) + v11 * ty;
    pd[o] = r0 * (1.0f - tx) + r1 * tx;
  }
  float c0 = a0 + pd[0] + bc[0];
  float c1 = a1 + pd[1] + bc[1];
  float b0 = a2 + pd[2] + bb[0];
  float b1 = a3 + pd[3] + bb[1];
  float b2 = a4 + pd[4] + bb[2];
  float b3 = a5 + pd[5] + bb[3];
  size_t nb = (size_t)b * N_PIX + n;
  float2 cv; cv.x = c0; cv.y = c1;
  *(float2*)(cls + nb * 2) = cv;
  float4 bv; bv.x = b0; bv.y = b1; bv.z = b2; bv.w = b3;
  *(float4*)(bbox + nb * 4) = bv;
  float m0 = fmaxf(c0, c1);
  float e0 = expf(c0 - m0), e1 = expf(c1 - m0);
  conf[nb] = e1 / (e0 + e1);
}

// ---------------- per-batch top-100 (R4-exact single kernel) ----------------------------
__global__ __launch_bounds__(1024) void k_topk(const float* __restrict__ conf,
                                               int* __restrict__ idx_out) {
  __shared__ unsigned int ord[N_PIX];
  __shared__ unsigned int whist[16][256];
  __shared__ unsigned int hist[256];
  __shared__ unsigned long long cand[512];
  __shared__ unsigned int s_cnt, s_prefix, s_ncand;
  int tid = threadIdx.x;
  int wv = tid >> 6;
  int b = blockIdx.x;
  const float* cb = conf + (size_t)b * N_PIX;
  for (int i = tid; i < N_PIX; i += 1024) {
    unsigned int u = __float_as_uint(cb[i]);
    ord[i] = (u & 0x80000000u) ? ~u : (u | 0x80000000u);
  }
  unsigned int prefix = 0, cnt_gt = 0;
  for (int pass = 0; pass < 4; ++pass) {
    int sh = 24 - 8 * pass;
    for (int i = tid; i < 16 * 256; i += 1024) ((unsigned int*)whist)[i] = 0;
    __syncthreads();
    unsigned int himask = (pass == 0) ? 0u : (0xFFFFFFFFu << (sh + 8));
    for (int i = tid; i < N_PIX; i += 1024) {
      unsigned int o = ord[i];
      if ((o & himask) == prefix) atomicAdd(&whist[wv][(o >> sh) & 255u], 1u);
    }
    __syncthreads();
    if (tid < 256) {
      unsigned int s = 0;
#pragma unroll
      for (int w2 = 0; w2 < 16; ++w2) s += whist[w2][tid];
      hist[tid] = s;
    }
    __syncthreads();
    if (tid == 0) {
      unsigned int c = cnt_gt; int v = 255;
      while (v > 0 && c + hist[v] < 100u) { c += hist[v]; --v; }
      s_cnt = c; s_prefix = prefix | ((unsigned int)v << sh);
    }
    __syncthreads();
    cnt_gt = s_cnt; prefix = s_prefix;
    __syncthreads();
  }
  if (tid == 0) s_ncand = 0;
  __syncthreads();
  unsigned int T = prefix;
  for (int i = tid; i < N_PIX; i += 1024) {
    unsigned int o = ord[i];
    if (o >= T) {
      unsigned int k = atomicAdd(&s_ncand, 1u);
      if (k < 512u)
        cand[k] = ((unsigned long long)o << 32) |
                  (unsigned long long)(0xFFFFFFFFu - (unsigned int)i);
    }
  }
  __syncthreads();
  unsigned int nc = s_ncand > 512u ? 512u : s_ncand;
  for (int i = tid; i < 512; i += 1024)
    if ((unsigned int)i >= nc) cand[i] = 0ull;
  __syncthreads();
  for (unsigned int k = 2; k <= 512; k <<= 1) {
    for (unsigned int j = k >> 1; j > 0; j >>= 1) {
      if (tid < 512) {
        unsigned int i = (unsigned int)tid, ixj = i ^ j;
        if (ixj > i) {
          unsigned long long a = cand[i], c2 = cand[ixj];
          bool up = ((i & k) == 0);
          if ((a > c2) == up) { cand[i] = c2; cand[ixj] = a; }
        }
      }
      __syncthreads();
    }
  }
  if (tid < 100) {
    unsigned long long key = cand[511 - tid];
    idx_out[b * 100 + tid] = (int)(0xFFFFFFFFu - (unsigned int)(key & 0xFFFFFFFFull));
  }
}

// ---------------- k_mlp3: 8 rows/block, thread = 4 outs x 2 rows, wT-coalesced ----------
// 32 FMA per 2 LDS b128 reads (8x the old ratio). 250 blocks: rows 0..1599 det, 1600..1999 rec.
__device__ __forceinline__ void mlp_layer8(const float (*in)[C_DIM], float (*outb)[C_DIM],
    const float* __restrict__ Wl, const float* __restrict__ bias, bool relu, int og, int lr0) {
  float4 bv = *(const float4*)(bias + og * 4);
  float4 a0 = bv, a1 = bv;
  const float* i0p = in[lr0];
  const float* i1p = in[lr0 + 1];
#pragma unroll 4
  for (int cq = 0; cq < 64; ++cq) {
    int c = cq * 4;
    float4 i0 = *(const float4*)(i0p + c);
    float4 i1 = *(const float4*)(i1p + c);
    float4 w0 = *(const float4*)(Wl + (size_t)(c + 0) * C_DIM + og * 4);
    float4 w1 = *(const float4*)(Wl + (size_t)(c + 1) * C_DIM + og * 4);
    float4 w2 = *(const float4*)(Wl + (size_t)(c + 2) * C_DIM + og * 4);
    float4 w3 = *(const float4*)(Wl + (size_t)(c + 3) * C_DIM + og * 4);
    a0.x = fmaf(w0.x, i0.x, a0.x); a0.y = fmaf(w0.y, i0.x, a0.y);
    a0.z = fmaf(w0.z, i0.x, a0.z); a0.w = fmaf(w0.w, i0.x, a0.w);
    a0.x = fmaf(w1.x, i0.y, a0.x); a0.y = fmaf(w1.y, i0.y, a0.y);
    a0.z = fmaf(w1.z, i0.y, a0.z); a0.w = fmaf(w1.w, i0.y, a0.w);
    a0.x = fmaf(w2.x, i0.z, a0.x); a0.y = fmaf(w2.y, i0.z, a0.y);
    a0.z = fmaf(w2.z, i0.z, a0.z); a0.w = fmaf(w2.w, i0.z, a0.w);
    a0.x = fmaf(w3.x, i0.w, a0.x); a0.y = fmaf(w3.y, i0.w, a0.y);
    a0.z = fmaf(w3.z, i0.w, a0.z); a0.w = fmaf(w3.w, i0.w, a0.w);
    a1.x = fmaf(w0.x, i1.x, a1.x); a1.y = fmaf(w0.y, i1.x, a1.y);
    a1.z = fmaf(w0.z, i1.x, a1.z); a1.w = fmaf(w0.w, i1.x, a1.w);
    a1.x = fmaf(w1.x, i1.y, a1.x); a1.y = fmaf(w1.y, i1.y, a1.y);
    a1.z = fmaf(w1.z, i1.y, a1.z); a1.w = fmaf(w1.w, i1.y, a1.w);
    a1.x = fmaf(w2.x, i1.z, a1.x); a1.y = fmaf(w2.y, i1.z, a1.y);
    a1.z = fmaf(w2.z, i1.z, a1.z); a1.w = fmaf(w2.w, i1.z, a1.w);
    a1.x = fmaf(w3.x, i1.w, a1.x); a1.y = fmaf(w3.y, i1.w, a1.y);
    a1.z = fmaf(w3.z, i1.w, a1.z); a1.w = fmaf(w3.w, i1.w, a1.w);
  }
  if (relu) {
    a0.x = fmaxf(a0.x, 0.f); a0.y = fmaxf(a0.y, 0.f); a0.z = fmaxf(a0.z, 0.f); a0.w = fmaxf(a0.w, 0.f);
    a1.x = fmaxf(a1.x, 0.f); a1.y = fmaxf(a1.y, 0.f); a1.z = fmaxf(a1.z, 0.f); a1.w = fmaxf(a1.w, 0.f);
  }
  *(float4*)(&outb[lr0][og * 4]) = a0;
  *(float4*)(&outb[lr0 + 1][og * 4]) = a1;
  __syncthreads();
}

__global__ __launch_bounds__(256) void k_mlp3(
    const float* __restrict__ x, const float* __restrict__ pe, const int* __restrict__ idx,
    const float* __restrict__ wT,
    const float* __restrict__ db1, const float* __restrict__ db2, const float* __restrict__ db3,
    const float* __restrict__ rb1, const float* __restrict__ rb2, const float* __restrict__ rb3,
    const float* __restrict__ det_q, const float* __restrict__ rec_q,
    float* __restrict__ det, float* __restrict__ rec) {
  __shared__ float bufA[8][C_DIM];
  __shared__ float bufB[8][C_DIM];
  int tid = threadIdx.x;
  int og = tid & 63, rg = tid >> 6;
  int base = blockIdx.x * 8;
  bool is_det = base < 1600;
  const float *W1, *W2, *W3, *B1, *B2, *B3;
  if (is_det) {
    W1 = wT;          W2 = wT + 65536;  W3 = wT + 131072;
    B1 = db1; B2 = db2; B3 = db3;
  } else {
    W1 = wT + 196608; W2 = wT + 262144; W3 = wT + 327680;
    B1 = rb1; B2 = rb2; B3 = rb3;
  }
  // gather x + recomputed pos (bilinear of pe at selected pixel), c = tid
  for (int lr = 0; lr < 8; ++lr) {
    int rowid = base + lr;
    int b, r;
    if (rowid < 1600) { b = rowid / 100; r = rowid % 100; }
    else { int t2 = rowid - 1600; b = t2 / 25; r = t2 % 25; }
    int n = idx[b * 100 + r];
    int y = n / 100, xq = n % 100;
    float sy = fminf(fmaxf((y + 0.5f) * 0.5f - 0.5f, 0.0f), 49.0f);
    float sx = fminf(fmaxf((xq + 0.5f) * 0.5f - 0.5f, 0.0f), 49.0f);
    int y0 = (int)floorf(sy); int y1 = min(y0 + 1, 49); float ty = sy - (float)y0;
    int x0i = (int)floorf(sx); int x1i = min(x0i + 1, 49); float tx = sx - (float)x0i;
    const float* p = pe + tid * 2500;
    float v00 = p[y0 * 50 + x0i], v01 = p[y0 * 50 + x1i];
    float v10 = p[y1 * 50 + x0i], v11 = p[y1 * 50 + x1i];
    float rr0 = v00 * (1.0f - ty) + v10 * ty;
    float rr1 = v01 * (1.0f - ty) + v11 * ty;
    float pv = rr0 * (1.0f - tx) + rr1 * tx;
    bufA[lr][tid] = x[((size_t)b * C_DIM + tid) * N_PIX + n] + pv;
  }
  __syncthreads();
  int lr0 = rg * 2;
  mlp_layer8(bufA, bufB, W1, B1, true,  og, lr0);
  mlp_layer8(bufB, bufA, W2, B2, true,  og, lr0);
  mlp_layer8(bufA, bufB, W3, B3, false, og, lr0);
  for (int lr = 0; lr < 8; ++lr) {
    int rowid = base + lr;
    if (rowid < 1600) {
      int r = rowid % 100;
      det[(size_t)rowid * C_DIM + tid] = bufB[lr][tid] + det_q[r * C_DIM + tid];
    } else {
      int t2 = rowid - 1600; int r = t2 % 25;
      rec[(size_t)t2 * C_DIM + tid] = bufB[lr][tid] + rec_q[r * C_DIM + tid];
    }
  }
}

extern "C" void kernel_launch(void* const* d_in, const int* in_sizes, int n_in,
                              void* d_out, int out_size, void* d_ws, size_t ws_size,
                              hipStream_t stream) {
  const float* x     = (const float*)d_in[0];
  const float* Wc    = (const float*)d_in[1];
  const float* bc    = (const float*)d_in[2];
  const float* Wb    = (const float*)d_in[3];
  const float* bb    = (const float*)d_in[4];
  const float* dW1   = (const float*)d_in[5];
  const float* db1   = (const float*)d_in[6];
  const float* dW2   = (const float*)d_in[7];
  const float* db2   = (const float*)d_in[8];
  const float* dW3   = (const float*)d_in[9];
  const float* db3   = (const float*)d_in[10];
  const float* rW1   = (const float*)d_in[11];
  const float* rb1   = (const float*)d_in[12];
  const float* rW2   = (const float*)d_in[13];
  const float* rb2   = (const float*)d_in[14];
  const float* rW3   = (const float*)d_in[15];
  const float* rb3   = (const float*)d_in[16];
  const float* det_q = (const float*)d_in[17];
  const float* rec_q = (const float*)d_in[18];
  const float* pos_e = (const float*)d_in[19];

  float* out  = (float*)d_out;
  float* det  = out;                // [16,100,256]  409600
  float* rec  = out + 409600;       // [16, 25,256]  102400
  float* cls  = out + 512000;       // [16,10000,2]  320000
  float* bbox = out + 832000;       // [16,10000,4]  640000

  // ws layout (bytes): wT @0 (1572864) | conf @1572864 (640000) | idx @2212864 | wpe @2221056
  char* wsb = (char*)d_ws;
  float* wT   = (float*)wsb;
  float* conf = (float*)(wsb + 1572864);
  int*   idx  = (int*)(wsb + 2212864);
  float* wpe  = (float*)(wsb + 2221056);

  k_prep<<<156, 256, 0, stream>>>(pos_e, Wc, Wb, dW1, dW2, dW3, rW1, rW2, rW3, wpe, wT);
  k_heads<<<dim3(40, B_SZ), 256, 0, stream>>>(x, wpe, Wc, bc, Wb, bb, cls, bbox, conf);
  k_topk<<<B_SZ, 1024, 0, stream>>>(conf, idx);
  k_mlp3<<<250, 256, 0, stream>>>(x, pos_e, idx, wT,
                                  db1, db2, db3, rb1, rb2, rb3,
                                  det_q, rec_q, det, rec);
}